// Round 4
// baseline (4588.430 us; speedup 1.0000x reference)
//
#include <hip/hip_runtime.h>
#include <stdint.h>

typedef float  f32x4 __attribute__((ext_vector_type(4)));
typedef short  s16x8 __attribute__((ext_vector_type(8)));
typedef unsigned int u32;
typedef unsigned long long u64;
typedef unsigned short bfu;
typedef long long i64;

#define B_ 256
#define T_ 256
#define I_ 128
#define H_ 512
#define O_ 128
#define CH 16
#define NCH (T_ / CH)
#define SLOTS ((size_t)CH * B_ * H_)   // elems per bf16 pre-array

__device__ __forceinline__ bfu f2b(float f) {
    u32 u = __float_as_uint(f);
    u += 0x7fffu + ((u >> 16) & 1u);
    return (bfu)(u >> 16);
}
__device__ __forceinline__ float b2f(bfu b) { return __uint_as_float(((u32)b) << 16); }
__device__ __forceinline__ float sigf(float x) { return 1.f / (1.f + __expf(-x)); }
__device__ __forceinline__ float tanhfast(float x) { return 1.f - 2.f / (__expf(2.f * x) + 1.f); }

// software float -> OCP e4m3fn, RNE, saturating
__device__ __forceinline__ unsigned char f2e4m3(float f) {
    u32 u = __float_as_uint(f);
    u32 s = (u >> 24) & 0x80u;
    u &= 0x7fffffffu;
    if (u >= 0x43e00000u) return (unsigned char)(s | 0x7eu);    // >= 448 -> sat
    if (u < 0x3c800000u) {                                       // < 2^-6 -> subnormal
        int m = __float2int_rn(__uint_as_float(u) * 512.f);
        if (m >= 8) return (unsigned char)(s | 0x08u);
        return (unsigned char)(s | (u32)m);
    }
    u += 0x7ffffu + ((u >> 20) & 1u);                            // RNE at bit 20
    u32 e8 = ((u >> 23) & 0xffu) - 120u;                         // bias 127 -> 7
    return (unsigned char)(s | (e8 << 3) | ((u >> 20) & 7u));
}

// ===========================================================================
// k_pack: weights -> MFMA B-fragment order.
// frag 16x16x32: lane L holds B[k = kt*32 + (L>>4)*8 + j][n = nt*16 + (L&15)].
// PW bf16 (W|V per gate), PG bf16 (Wgh), PUc bf16 (Uc), PU8 fp8 (Uz,Ur x32).
// ===========================================================================
__global__ __launch_bounds__(256) void k_pack(
    const float* __restrict__ Wz, const float* __restrict__ Wr, const float* __restrict__ Wc,
    const float* __restrict__ Vz, const float* __restrict__ Vr, const float* __restrict__ Vc,
    const float* __restrict__ Wgh,
    const float* __restrict__ Uz, const float* __restrict__ Ur, const float* __restrict__ Uc,
    short* __restrict__ PW, short* __restrict__ PG, short* __restrict__ PUc,
    unsigned char* __restrict__ PU8)
{
    int wv = blockIdx.x * 4 + (threadIdx.x >> 6);
    int L = threadIdx.x & 63;
    if (wv >= 2432) return;
    int koff = (L >> 4) << 3;
    int ncol;
    if (wv < 768) {                       // PW: gate x (kt<4:W, kt>=4:V)
        int g = wv >> 8, rem = wv & 255;
        int kt = rem >> 5; ncol = (rem & 31) * 16 + (L & 15);
        const float* src = (kt < 4) ? (g == 0 ? Wz : g == 1 ? Wr : Wc)
                                    : (g == 0 ? Vz : g == 1 ? Vr : Vc);
        int kbase = (kt & 3) * 32 + koff;
        s16x8 v;
        #pragma unroll
        for (int j = 0; j < 8; ++j) v[j] = (short)f2b(src[(kbase + j) * H_ + ncol]);
        *(s16x8*)&PW[((size_t)(g * 256 + rem) * 64 + L) * 8] = v;
    } else if (wv < 896) {                // PG
        int rem = wv - 768;
        ncol = (rem & 31) * 16 + (L & 15);
        int kbase = (rem >> 5) * 32 + koff;
        s16x8 v;
        #pragma unroll
        for (int j = 0; j < 8; ++j) v[j] = (short)f2b(Wgh[(kbase + j) * H_ + ncol]);
        *(s16x8*)&PG[((size_t)rem * 64 + L) * 8] = v;
    } else if (wv < 1408) {               // PUc bf16
        int rem = wv - 896;               // kt*32+nt, kt 0..15
        ncol = (rem & 31) * 16 + (L & 15);
        int kbase = (rem >> 5) * 32 + koff;
        s16x8 v;
        #pragma unroll
        for (int j = 0; j < 8; ++j) v[j] = (short)f2b(Uc[(kbase + j) * H_ + ncol]);
        *(s16x8*)&PUc[((size_t)rem * 64 + L) * 8] = v;
    } else {                              // PU8: Uz, Ur scaled x32, e4m3
        int rem = wv - 1408;              // g*512 + kt*32 + nt
        int g = rem >> 9, r2 = rem & 511;
        ncol = (r2 & 31) * 16 + (L & 15);
        int kbase = (r2 >> 5) * 32 + koff;
        const float* src = (g == 0) ? Uz : Ur;
        unsigned char* d = PU8 + ((size_t)rem * 64 + L) * 8;
        #pragma unroll
        for (int j = 0; j < 8; ++j) d[j] = f2e4m3(src[(kbase + j) * H_ + ncol] * 32.f);
    }
}

// ===========================================================================
// k1 unit: input-side projections for one batch row b, 16 timesteps.
// 512 threads (8 waves x 64 cols). bf16 outputs, layout [tl][b][H].
// ===========================================================================
__device__ void k1_unit(char* sm, int b, int t0,
    const float* __restrict__ x, const float* __restrict__ dl,
    const float* __restrict__ mk, const float* __restrict__ xf,
    const float* __restrict__ bz, const float* __restrict__ br, const float* __restrict__ bc,
    const float* __restrict__ Bgh,
    const float* __restrict__ Wgx, const float* __restrict__ Bgx,
    const short* __restrict__ PW, const short* __restrict__ PG,
    bfu* __restrict__ pz, bfu* __restrict__ pr, bfu* __restrict__ pc, bfu* __restrict__ gm)
{
    short* Abuf = (short*)sm;             // 12 KB: [kt 0..11][lane][8]
    const int t = threadIdx.x & 511;
    const int L = t & 63, w = t >> 6;

    for (int cc = t; cc < 12 * 64; cc += 512) {
        int Ls = cc & 63, kt = cc >> 6;
        int tl = Ls & 15, q = Ls >> 4;
        int gbase = (b * T_ + t0 + tl) * I_;
        s16x8 v;
        if (kt < 4) {
            int kb = kt * 32 + q * 8;
            f32x4 m0 = *(const f32x4*)&mk[gbase + kb], m1 = *(const f32x4*)&mk[gbase + kb + 4];
            f32x4 d0 = *(const f32x4*)&dl[gbase + kb], d1 = *(const f32x4*)&dl[gbase + kb + 4];
            f32x4 f0 = *(const f32x4*)&xf[gbase + kb], f1 = *(const f32x4*)&xf[gbase + kb + 4];
            f32x4 x0 = *(const f32x4*)&x[gbase + kb],  x1 = *(const f32x4*)&x[gbase + kb + 4];
            #pragma unroll
            for (int j = 0; j < 8; ++j) {
                int k = kb + j;
                float mv = (j < 4) ? m0[j] : m1[j - 4];
                float dv = (j < 4) ? d0[j] : d1[j - 4];
                float fv = (j < 4) ? f0[j] : f1[j - 4];
                float xv = (j < 4) ? x0[j] : x1[j - 4];
                float dx = dv * Wgx[k] + Bgx[k];
                float xr = dx * fv + (1.f - dx) * 0.001f;
                v[j] = (short)f2b((mv > 0.5f) ? xr : xv);
            }
        } else if (kt < 8) {
            int kb = (kt - 4) * 32 + q * 8;
            f32x4 m0 = *(const f32x4*)&mk[gbase + kb], m1 = *(const f32x4*)&mk[gbase + kb + 4];
            #pragma unroll
            for (int j = 0; j < 8; ++j) v[j] = (short)f2b(1.f - ((j < 4) ? m0[j] : m1[j - 4]));
        } else {
            int kb = (kt - 8) * 32 + q * 8;
            f32x4 m0 = *(const f32x4*)&mk[gbase + kb], m1 = *(const f32x4*)&mk[gbase + kb + 4];
            #pragma unroll
            for (int j = 0; j < 8; ++j) v[j] = (short)f2b((j < 4) ? m0[j] : m1[j - 4]);
        }
        *(s16x8*)&Abuf[(size_t)cc * 8] = v;
    }
    __syncthreads();

    const s16x8* PWf = (const s16x8*)PW;
    const s16x8* PGf = (const s16x8*)PG;

    for (int g = 0; g < 3; ++g) {
        f32x4 acc[4];
        #pragma unroll
        for (int nt = 0; nt < 4; ++nt) acc[nt] = (f32x4)0.f;
        for (int kt = 0; kt < 8; ++kt) {
            s16x8 a = *(const s16x8*)&Abuf[(kt * 64 + L) * 8];
            const s16x8* pw = PWf + ((size_t)(g * 256 + kt * 32 + w * 4) * 64 + L);
            #pragma unroll
            for (int nt = 0; nt < 4; ++nt)
                acc[nt] = __builtin_amdgcn_mfma_f32_16x16x32_bf16(a, pw[(size_t)nt * 64], acc[nt], 0, 0, 0);
        }
        const float* bias = (g == 0) ? bz : (g == 1) ? br : bc;
        bfu* dst = (g == 0) ? pz : (g == 1) ? pr : pc;
        #pragma unroll
        for (int nt = 0; nt < 4; ++nt) {
            int n = w * 64 + nt * 16 + (L & 15);
            float bv = bias[n];
            #pragma unroll
            for (int reg = 0; reg < 4; ++reg) {
                int tl = (L >> 4) * 4 + reg;
                dst[(size_t)(tl * B_ + b) * H_ + n] = f2b(acc[nt][reg] + bv);
            }
        }
    }
    {
        f32x4 acc[4];
        #pragma unroll
        for (int nt = 0; nt < 4; ++nt) acc[nt] = (f32x4)0.f;
        for (int kk = 0; kk < 4; ++kk) {
            s16x8 a = *(const s16x8*)&Abuf[((8 + kk) * 64 + L) * 8];
            const s16x8* pg = PGf + ((size_t)(kk * 32 + w * 4) * 64 + L);
            #pragma unroll
            for (int nt = 0; nt < 4; ++nt)
                acc[nt] = __builtin_amdgcn_mfma_f32_16x16x32_bf16(a, pg[(size_t)nt * 64], acc[nt], 0, 0, 0);
        }
        #pragma unroll
        for (int nt = 0; nt < 4; ++nt) {
            int n = w * 64 + nt * 16 + (L & 15);
            float bv = Bgh[n];
            #pragma unroll
            for (int reg = 0; reg < 4; ++reg) {
                int tl = (L >> 4) * 4 + reg;
                gm[(size_t)(tl * B_ + b) * H_ + n] = f2b(__expf(-fmaxf(acc[nt][reg] + bv, 0.f)));
            }
        }
    }
}

// ===========================================================================
// scan block (pair-split): blocks (p, hb): pair p handles rows [16p,16p+16);
// half hb owns H-columns [hb*256, +256) for z/r (column-split, full K) and
// K-rows [hb*256, +256) for the c GEMM (K-split, all columns).
// wz (Uz fp8 slice, 16 KB/wave) is register-resident across all 16 steps.
// Export is LDS-staged + coalesced u64 agent atomics (R3 structure); import
// is direct-to-register (64-B segments), removing one barrier + LDS trip.
// ===========================================================================
__device__ void scan_block(char* sm, int p, int hb, int base, const bfu* __restrict__ pre,
                           const short* __restrict__ PUc, const unsigned char* __restrict__ PU8,
                           float* __restrict__ hws,
                           float* __restrict__ zx, float* __restrict__ cx,
                           u32* __restrict__ flags)
{
    char*  Abf8 = sm;                        // 8 KB fp8 A-fragments [16 kt][64][8] (full K)
    short* Apbf = (short*)(sm + 8192);       // 8 KB bf16 (A*r)-fragments, own K-half
    float* rl   = (float*)(sm + 16384);      // 16 KB f32 [16][256]: own r
    float* zl   = (float*)(sm + 32768);      // 16 KB f32 [16][256]: own z
    float* cp   = (float*)(sm + 49152);      // 32 KB f32 [16][512]: own c-partials (export staging)
    const bfu* pz = pre;
    const bfu* pr = pre + SLOTS;
    const bfu* pc = pre + 2 * SLOTS;
    const bfu* gm = pre + 3 * SLOTS;
    const int tid = threadIdx.x, L = tid & 63, w = tid >> 6;
    const int b0 = p * 16;
    const i64* PU8q = (const i64*)PU8;
    const s16x8* PUcf = (const s16x8*)PUc;
    const float INV = 4.8828125e-4f;        // 1/2048

    int nn[2], ktq[2], lsh[2], j2;
    #pragma unroll
    for (int nt = 0; nt < 2; ++nt) {
        nn[nt] = w * 32 + nt * 16 + (L & 15);
        ktq[nt] = nn[nt] >> 5;
        lsh[nt] = ((nn[nt] >> 3) & 3) << 4;
    }
    j2 = nn[0] & 7;
    const int row0 = (L >> 4) * 4;
    const int clzr = w * 16 + (L & 15);      // local col in own 256-slice (z/r mapping)
    const int nzr = hb * 256 + clzr;         // global col (z/r mapping)
    const int ph = w >> 3;                   // half that this wave's nn cols live in

    float* zxO0 = zx + (size_t)(p * 2 + hb) * 2 * 4096;
    float* cxO0 = cx + (size_t)(p * 2 + hb) * 2 * 8192;
    float* zxP0 = zx + (size_t)(p * 2 + (1 - hb)) * 2 * 4096;
    float* cxP0 = cx + (size_t)(p * 2 + (1 - hb)) * 2 * 8192;
    u32* flagO = flags + (size_t)(p * 2 + hb) * 32;
    u32* flagP = flags + (size_t)(p * 2 + (1 - hb)) * 32;

    // ---- wz register-resident across the whole chunk (32 VGPRs) ----
    i64 wzr[16];
    #pragma unroll
    for (int kt = 0; kt < 16; ++kt)
        wzr[kt] = PU8q[((size_t)(kt * 32 + hb * 16 + w)) * 64 + L];

    float A32[2][4];
    #pragma unroll
    for (int nt = 0; nt < 2; ++nt)
        #pragma unroll
        for (int reg = 0; reg < 4; ++reg) {
            int row = row0 + reg;
            float h = hws[(size_t)(b0 + row) * H_ + nn[nt]];
            float gv = b2f(gm[(size_t)(b0 + row) * H_ + nn[nt]]);   // tl = 0
            float A = gv * h;
            A32[nt][reg] = A;
            Abf8[(ktq[nt] * 64 + (row | lsh[nt])) * 8 + j2] = f2e4m3(A * 64.f);
        }
    __syncthreads();

    // lpz/lpr for tl=0 (later steps prefetched in the exchange window)
    float lpzv[4], lprv[4];
    #pragma unroll
    for (int reg = 0; reg < 4; ++reg) {
        int row = b0 + row0 + reg;
        lpzv[reg] = b2f(pz[(size_t)(0 * B_ + row) * H_ + nzr]);
        lprv[reg] = b2f(pr[(size_t)(0 * B_ + row) * H_ + nzr]);
    }

    for (int tl = 0; tl < CH; ++tl) {
        const int S = base + tl;
        const int par = S & 1;
        u64* zxOq = (u64*)(zxO0 + par * 4096);
        u64* cxOq = (u64*)(cxO0 + par * 8192);
        const float* zxPf = zxP0 + par * 4096;
        const float* cxPf = cxP0 + par * 8192;
        int tln = (tl + 1 < CH) ? tl + 1 : tl;

        // ---- phase A: z/r fp8 GEMMs, own 16 cols per wave, full K ----
        // wz from registers; wr streamed from L2.
        f32x4 az = (f32x4)0.f, ar = (f32x4)0.f;
        #pragma unroll 8
        for (int kt = 0; kt < 16; ++kt) {
            i64 a8 = *(const i64*)&Abf8[(kt * 64 + L) * 8];
            i64 br8 = PU8q[((size_t)(512 + kt * 32 + hb * 16 + w)) * 64 + L];
            az = __builtin_amdgcn_mfma_f32_16x16x32_fp8_fp8(a8, wzr[kt], az, 0, 0, 0);
            ar = __builtin_amdgcn_mfma_f32_16x16x32_fp8_fp8(a8, br8, ar, 0, 0, 0);
        }
        #pragma unroll
        for (int reg = 0; reg < 4; ++reg) {
            int m = row0 + reg;
            float zg = sigf(az[reg] * INV + lpzv[reg]);
            float rg = sigf(ar[reg] * INV + lprv[reg]);
            zl[m * 256 + clzr] = zg;
            rl[m * 256 + clzr] = rg;
        }
        __syncthreads();   // (1) zl/rl complete

        // ---- export z (coalesced u64), overlaps build + c GEMM ----
        {
            const u64* zlq = (const u64*)zl;
            __hip_atomic_store(&zxOq[tid], zlq[tid], __ATOMIC_RELAXED, __HIP_MEMORY_SCOPE_AGENT);
            __hip_atomic_store(&zxOq[tid + 1024], zlq[tid + 1024], __ATOMIC_RELAXED, __HIP_MEMORY_SCOPE_AGENT);
        }

        // ---- build (A*r) bf16 A-fragments for own K-half ----
        if (ph == hb) {
            #pragma unroll
            for (int nt = 0; nt < 2; ++nt) {
                int kl = nn[nt] & 255;
                int ktql = kl >> 5;
                #pragma unroll
                for (int reg = 0; reg < 4; ++reg) {
                    int m = row0 + reg;
                    Apbf[(ktql * 64 + (m | lsh[nt])) * 8 + j2] = (short)f2b(A32[nt][reg] * rl[m * 256 + kl]);
                }
            }
        }
        __syncthreads();   // (2) Apbf complete

        // ---- c bf16 GEMM: all cols, own K-half ----
        f32x4 ac[2];
        ac[0] = (f32x4)0.f; ac[1] = (f32x4)0.f;
        #pragma unroll 4
        for (int kk = 0; kk < 8; ++kk) {
            s16x8 a = *(const s16x8*)&Apbf[(kk * 64 + L) * 8];
            const s16x8* c8 = PUcf + ((size_t)((hb * 8 + kk) * 32 + w * 2) * 64 + L);
            s16x8 bc0 = c8[0], bc1 = c8[64];
            ac[0] = __builtin_amdgcn_mfma_f32_16x16x32_bf16(a, bc0, ac[0], 0, 0, 0);
            ac[1] = __builtin_amdgcn_mfma_f32_16x16x32_bf16(a, bc1, ac[1], 0, 0, 0);
        }
        #pragma unroll
        for (int nt = 0; nt < 2; ++nt)
            #pragma unroll
            for (int reg = 0; reg < 4; ++reg)
                cp[(row0 + reg) * 512 + nn[nt]] = ac[nt][reg];
        __syncthreads();   // (3) cp complete

        // ---- export c-partials (coalesced u64) ----
        {
            const u64* cpq = (const u64*)cp;
            #pragma unroll
            for (int i = 0; i < 4; ++i)
                __hip_atomic_store(&cxOq[tid + i * 1024], cpq[tid + i * 1024],
                                   __ATOMIC_RELAXED, __HIP_MEMORY_SCOPE_AGENT);
        }
        __syncthreads();   // (4) all waves' exports drained (vmcnt 0 before barrier)
        if (tid == 0)
            __hip_atomic_store(flagO, (u32)(S + 1), __ATOMIC_RELEASE, __HIP_MEMORY_SCOPE_AGENT);

        // ---- prefetch update operands (this tl) + lpz/lpr (next tl);
        //      latency hides under partner round-trip ----
        float lpcv[2][4], lgmv[2][4];
        #pragma unroll
        for (int nt = 0; nt < 2; ++nt)
            #pragma unroll
            for (int reg = 0; reg < 4; ++reg) {
                int row = b0 + row0 + reg;
                lpcv[nt][reg] = b2f(pc[(size_t)(tl * B_ + row) * H_ + nn[nt]]);
                lgmv[nt][reg] = b2f(gm[(size_t)(tln * B_ + row) * H_ + nn[nt]]);
            }
        #pragma unroll
        for (int reg = 0; reg < 4; ++reg) {
            int row = b0 + row0 + reg;
            lpzv[reg] = b2f(pz[(size_t)(tln * B_ + row) * H_ + nzr]);
            lprv[reg] = b2f(pr[(size_t)(tln * B_ + row) * H_ + nzr]);
        }

        if (tid == 0) {
            while (__hip_atomic_load(flagP, __ATOMIC_RELAXED, __HIP_MEMORY_SCOPE_AGENT) < (u32)(S + 1))
                __builtin_amdgcn_s_sleep(1);
        }
        __syncthreads();   // (5) partner data ready

        // ---- state update; partner z / c-partials read direct to registers ----
        #pragma unroll
        for (int nt = 0; nt < 2; ++nt) {
            int kl = nn[nt] & 255;
            #pragma unroll
            for (int reg = 0; reg < 4; ++reg) {
                int m = row0 + reg;
                float cpe = __hip_atomic_load(&cxPf[m * 512 + nn[nt]],
                                              __ATOMIC_RELAXED, __HIP_MEMORY_SCOPE_AGENT);
                float zg;
                if (ph == hb) zg = zl[m * 256 + kl];
                else zg = __hip_atomic_load(&zxPf[m * 256 + kl],
                                            __ATOMIC_RELAXED, __HIP_MEMORY_SCOPE_AGENT);
                float cc = tanhfast(ac[nt][reg] + cpe + lpcv[nt][reg]);
                float hn = (1.f - zg) * A32[nt][reg] + zg * cc;
                if (tl < CH - 1) {
                    float An = lgmv[nt][reg] * hn;
                    A32[nt][reg] = An;
                    Abf8[(ktq[nt] * 64 + (m | lsh[nt])) * 8 + j2] = f2e4m3(An * 64.f);
                } else if (ph == hb) {
                    hws[(size_t)(b0 + m) * H_ + nn[nt]] = hn;
                }
            }
        }
        __syncthreads();   // (6) Abf8/zl/rl safe to overwrite next step
    }
}

// ===========================================================================
// fused launch: blocks 0-31 scan chunk c-1 (16 pairs x 2 halves);
// blocks 32-159 (2x512-thr units) compute pre-activations for chunk c.
// ===========================================================================
__global__ __launch_bounds__(1024, 4) void k_fused(int c,
    const float* __restrict__ x, const float* __restrict__ dl,
    const float* __restrict__ mk, const float* __restrict__ xf,
    const float* __restrict__ bz, const float* __restrict__ br, const float* __restrict__ bc,
    const float* __restrict__ Bgh,
    const float* __restrict__ Wgx, const float* __restrict__ Bgx,
    const short* __restrict__ PW, const short* __restrict__ PG,
    const short* __restrict__ PUc, const unsigned char* __restrict__ PU8,
    bfu* __restrict__ buf0, bfu* __restrict__ buf1, float* __restrict__ hws,
    float* __restrict__ zx, float* __restrict__ cx, u32* __restrict__ flags)
{
    __shared__ char sm[81920];
    if (blockIdx.x < 32) {
        if (c == 0) return;
        const bfu* pre = (c & 1) ? buf0 : buf1;    // chunk c-1 lives in buf[(c-1)&1]
        int p = blockIdx.x & 15, hb = blockIdx.x >> 4;
        scan_block(sm, p, hb, (c - 1) * CH, pre, PUc, PU8, hws, zx, cx, flags);
    } else {
        if (c >= NCH) return;
        int unit = ((int)blockIdx.x - 32) * 2 + (threadIdx.x >> 9);
        if (unit >= B_) return;
        bfu* dst = (c & 1) ? buf1 : buf0;           // chunk c -> buf[c&1]
        k1_unit(sm + (threadIdx.x >> 9) * 12288, unit, c * CH,
                x, dl, mk, xf, bz, br, bc, Bgh, Wgx, Bgx, PW, PG,
                dst, dst + SLOTS, dst + 2 * SLOTS, dst + 3 * SLOTS);
    }
}

// ===========================================================================
// k3: BatchNorm(eval) + decoder GEMV + log_softmax.
// ===========================================================================
__global__ __launch_bounds__(128) void k3_out(
    const float* __restrict__ hws,
    const float* __restrict__ dW, const float* __restrict__ db,
    const float* __restrict__ bng, const float* __restrict__ bnb,
    float* __restrict__ out)
{
    __shared__ float hb[H_];
    __shared__ float red[O_];
    const int tid = threadIdx.x;
    const int b = blockIdx.x;
    const float s = 0.9999950000374997f;   // 1/sqrt(1 + 1e-5)
    for (int k = tid; k < H_; k += O_) {
        float v = hws[(size_t)b * H_ + k] * s * bng[k] + bnb[k];
        hb[k] = v;
        out[B_ * O_ + (size_t)b * H_ + k] = v;
    }
    __syncthreads();
    float acc = db[tid];
    #pragma unroll 4
    for (int k = 0; k < H_; ++k) acc += hb[k] * dW[(size_t)k * O_ + tid];
    red[tid] = acc;
    __syncthreads();
    for (int sh = 64; sh > 0; sh >>= 1) {
        if (tid < sh) red[tid] = fmaxf(red[tid], red[tid + sh]);
        __syncthreads();
    }
    float mx = red[0];
    __syncthreads();
    red[tid] = __expf(acc - mx);
    __syncthreads();
    for (int sh = 64; sh > 0; sh >>= 1) {
        if (tid < sh) red[tid] += red[tid + sh];
        __syncthreads();
    }
    float lse = __logf(red[0]) + mx;
    out[(size_t)b * O_ + tid] = acc - lse;
}

extern "C" void kernel_launch(void* const* d_in, const int* in_sizes, int n_in,
                              void* d_out, int out_size, void* d_ws, size_t ws_size,
                              hipStream_t stream)
{
    (void)in_sizes; (void)n_in; (void)out_size; (void)ws_size;
    const float* x   = (const float*)d_in[0];
    const float* dl  = (const float*)d_in[1];
    const float* m   = (const float*)d_in[2];
    const float* xf  = (const float*)d_in[3];
    const float* Wr  = (const float*)d_in[4];
    const float* Ur  = (const float*)d_in[5];
    const float* Vr  = (const float*)d_in[6];
    const float* br  = (const float*)d_in[7];
    const float* Wz  = (const float*)d_in[8];
    const float* Uz  = (const float*)d_in[9];
    const float* Vz  = (const float*)d_in[10];
    const float* bz  = (const float*)d_in[11];
    const float* Wc  = (const float*)d_in[12];
    const float* Uc  = (const float*)d_in[13];
    const float* Vc  = (const float*)d_in[14];
    const float* bc  = (const float*)d_in[15];
    const float* Wgx = (const float*)d_in[16];
    const float* Bgx = (const float*)d_in[17];
    const float* Wgh = (const float*)d_in[18];
    const float* Bgh = (const float*)d_in[19];
    const float* dW  = (const float*)d_in[20];
    const float* db  = (const float*)d_in[21];
    const float* bng = (const float*)d_in[22];
    const float* bnb = (const float*)d_in[23];

    char* p = (char*)d_ws;
    short* PW = (short*)p;              p += (size_t)3 * 256 * 64 * 8 * 2;   // 768 KB
    short* PG = (short*)p;              p += (size_t)128 * 64 * 8 * 2;       // 128 KB
    short* PUc = (short*)p;             p += (size_t)512 * 64 * 8 * 2;       // 512 KB
    unsigned char* PU8 = (unsigned char*)p; p += (size_t)1024 * 64 * 8;      // 512 KB
    bfu* buf0 = (bfu*)p;                p += 4 * SLOTS * 2;                  // 16 MB
    bfu* buf1 = (bfu*)p;                p += 4 * SLOTS * 2;                  // 16 MB
    float* hws = (float*)p;             p += (size_t)B_ * H_ * 4;            // 512 KB
    float* zx  = (float*)p;             p += (size_t)16 * 2 * 2 * 4096 * 4;  // 1 MB
    float* cx  = (float*)p;             p += (size_t)16 * 2 * 2 * 8192 * 4;  // 2 MB
    u32* flags = (u32*)p;                                                    // 4 KB

    hipMemsetAsync(hws, 0, (size_t)B_ * H_ * sizeof(float), stream);
    hipMemsetAsync(flags, 0, (size_t)32 * 32 * sizeof(u32), stream);
    k_pack<<<dim3(608), dim3(256), 0, stream>>>(Wz, Wr, Wc, Vz, Vr, Vc, Wgh,
                                                Uz, Ur, Uc, PW, PG, PUc, PU8);
    for (int c = 0; c <= NCH; ++c) {
        k_fused<<<dim3(160), dim3(1024), 0, stream>>>(c,
            x, dl, m, xf, bz, br, bc, Bgh, Wgx, Bgx,
            PW, PG, PUc, PU8, buf0, buf1, hws, zx, cx, flags);
    }
    k3_out<<<dim3(B_), dim3(O_), 0, stream>>>(hws, dW, db, bng, bnb, (float*)d_out);
}

// Round 5
// 3861.759 us; speedup vs baseline: 1.1882x; 1.1882x over previous
//
#include <hip/hip_runtime.h>
#include <stdint.h>

typedef float  f32x4 __attribute__((ext_vector_type(4)));
typedef short  s16x8 __attribute__((ext_vector_type(8)));
typedef unsigned int u32;
typedef unsigned long long u64;
typedef unsigned short bfu;
typedef long long i64;

#define B_ 256
#define T_ 256
#define I_ 128
#define H_ 512
#define O_ 128
#define CH 16
#define NCH (T_ / CH)
#define SLOTS ((size_t)CH * B_ * H_)   // elems per bf16 pre-array

__device__ __forceinline__ bfu f2b(float f) {
    u32 u = __float_as_uint(f);
    u += 0x7fffu + ((u >> 16) & 1u);
    return (bfu)(u >> 16);
}
__device__ __forceinline__ float b2f(bfu b) { return __uint_as_float(((u32)b) << 16); }
__device__ __forceinline__ float sigf(float x) { return 1.f / (1.f + __expf(-x)); }
__device__ __forceinline__ float tanhfast(float x) { return 1.f - 2.f / (__expf(2.f * x) + 1.f); }

// software float -> OCP e4m3fn, RNE, saturating
__device__ __forceinline__ unsigned char f2e4m3(float f) {
    u32 u = __float_as_uint(f);
    u32 s = (u >> 24) & 0x80u;
    u &= 0x7fffffffu;
    if (u >= 0x43e00000u) return (unsigned char)(s | 0x7eu);    // >= 448 -> sat
    if (u < 0x3c800000u) {                                       // < 2^-6 -> subnormal
        int m = __float2int_rn(__uint_as_float(u) * 512.f);
        if (m >= 8) return (unsigned char)(s | 0x08u);
        return (unsigned char)(s | (u32)m);
    }
    u += 0x7ffffu + ((u >> 20) & 1u);                            // RNE at bit 20
    u32 e8 = ((u >> 23) & 0xffu) - 120u;                         // bias 127 -> 7
    return (unsigned char)(s | (e8 << 3) | ((u >> 20) & 7u));
}

// ===========================================================================
// k_pack: weights -> MFMA B-fragment order.
// frag 16x16x32: lane L holds B[k = kt*32 + (L>>4)*8 + j][n = nt*16 + (L&15)].
// PW bf16 (W|V per gate), PG bf16 (Wgh), PUc bf16 (Uc), PU8 fp8 (Uz,Ur x32).
// ===========================================================================
__global__ __launch_bounds__(256) void k_pack(
    const float* __restrict__ Wz, const float* __restrict__ Wr, const float* __restrict__ Wc,
    const float* __restrict__ Vz, const float* __restrict__ Vr, const float* __restrict__ Vc,
    const float* __restrict__ Wgh,
    const float* __restrict__ Uz, const float* __restrict__ Ur, const float* __restrict__ Uc,
    short* __restrict__ PW, short* __restrict__ PG, short* __restrict__ PUc,
    unsigned char* __restrict__ PU8)
{
    int wv = blockIdx.x * 4 + (threadIdx.x >> 6);
    int L = threadIdx.x & 63;
    if (wv >= 2432) return;
    int koff = (L >> 4) << 3;
    int ncol;
    if (wv < 768) {                       // PW: gate x (kt<4:W, kt>=4:V)
        int g = wv >> 8, rem = wv & 255;
        int kt = rem >> 5; ncol = (rem & 31) * 16 + (L & 15);
        const float* src = (kt < 4) ? (g == 0 ? Wz : g == 1 ? Wr : Wc)
                                    : (g == 0 ? Vz : g == 1 ? Vr : Vc);
        int kbase = (kt & 3) * 32 + koff;
        s16x8 v;
        #pragma unroll
        for (int j = 0; j < 8; ++j) v[j] = (short)f2b(src[(kbase + j) * H_ + ncol]);
        *(s16x8*)&PW[((size_t)(g * 256 + rem) * 64 + L) * 8] = v;
    } else if (wv < 896) {                // PG
        int rem = wv - 768;
        ncol = (rem & 31) * 16 + (L & 15);
        int kbase = (rem >> 5) * 32 + koff;
        s16x8 v;
        #pragma unroll
        for (int j = 0; j < 8; ++j) v[j] = (short)f2b(Wgh[(kbase + j) * H_ + ncol]);
        *(s16x8*)&PG[((size_t)rem * 64 + L) * 8] = v;
    } else if (wv < 1408) {               // PUc bf16
        int rem = wv - 896;               // kt*32+nt, kt 0..15
        ncol = (rem & 31) * 16 + (L & 15);
        int kbase = (rem >> 5) * 32 + koff;
        s16x8 v;
        #pragma unroll
        for (int j = 0; j < 8; ++j) v[j] = (short)f2b(Uc[(kbase + j) * H_ + ncol]);
        *(s16x8*)&PUc[((size_t)rem * 64 + L) * 8] = v;
    } else {                              // PU8: Uz, Ur scaled x32, e4m3
        int rem = wv - 1408;              // g*512 + kt*32 + nt
        int g = rem >> 9, r2 = rem & 511;
        ncol = (r2 & 31) * 16 + (L & 15);
        int kbase = (r2 >> 5) * 32 + koff;
        const float* src = (g == 0) ? Uz : Ur;
        unsigned char* d = PU8 + ((size_t)rem * 64 + L) * 8;
        #pragma unroll
        for (int j = 0; j < 8; ++j) d[j] = f2e4m3(src[(kbase + j) * H_ + ncol] * 32.f);
    }
}

// ===========================================================================
// k1 unit: input-side projections for one batch row b, 16 timesteps.
// 512 threads (8 waves x 64 cols). bf16 outputs, layout [tl][b][H].
// ===========================================================================
__device__ void k1_unit(char* sm, int b, int t0,
    const float* __restrict__ x, const float* __restrict__ dl,
    const float* __restrict__ mk, const float* __restrict__ xf,
    const float* __restrict__ bz, const float* __restrict__ br, const float* __restrict__ bc,
    const float* __restrict__ Bgh,
    const float* __restrict__ Wgx, const float* __restrict__ Bgx,
    const short* __restrict__ PW, const short* __restrict__ PG,
    bfu* __restrict__ pz, bfu* __restrict__ pr, bfu* __restrict__ pc, bfu* __restrict__ gm)
{
    short* Abuf = (short*)sm;             // 12 KB: [kt 0..11][lane][8]
    const int t = threadIdx.x & 511;
    const int L = t & 63, w = t >> 6;

    for (int cc = t; cc < 12 * 64; cc += 512) {
        int Ls = cc & 63, kt = cc >> 6;
        int tl = Ls & 15, q = Ls >> 4;
        int gbase = (b * T_ + t0 + tl) * I_;
        s16x8 v;
        if (kt < 4) {
            int kb = kt * 32 + q * 8;
            f32x4 m0 = *(const f32x4*)&mk[gbase + kb], m1 = *(const f32x4*)&mk[gbase + kb + 4];
            f32x4 d0 = *(const f32x4*)&dl[gbase + kb], d1 = *(const f32x4*)&dl[gbase + kb + 4];
            f32x4 f0 = *(const f32x4*)&xf[gbase + kb], f1 = *(const f32x4*)&xf[gbase + kb + 4];
            f32x4 x0 = *(const f32x4*)&x[gbase + kb],  x1 = *(const f32x4*)&x[gbase + kb + 4];
            #pragma unroll
            for (int j = 0; j < 8; ++j) {
                int k = kb + j;
                float mv = (j < 4) ? m0[j] : m1[j - 4];
                float dv = (j < 4) ? d0[j] : d1[j - 4];
                float fv = (j < 4) ? f0[j] : f1[j - 4];
                float xv = (j < 4) ? x0[j] : x1[j - 4];
                float dx = dv * Wgx[k] + Bgx[k];
                float xr = dx * fv + (1.f - dx) * 0.001f;
                v[j] = (short)f2b((mv > 0.5f) ? xr : xv);
            }
        } else if (kt < 8) {
            int kb = (kt - 4) * 32 + q * 8;
            f32x4 m0 = *(const f32x4*)&mk[gbase + kb], m1 = *(const f32x4*)&mk[gbase + kb + 4];
            #pragma unroll
            for (int j = 0; j < 8; ++j) v[j] = (short)f2b(1.f - ((j < 4) ? m0[j] : m1[j - 4]));
        } else {
            int kb = (kt - 8) * 32 + q * 8;
            f32x4 m0 = *(const f32x4*)&mk[gbase + kb], m1 = *(const f32x4*)&mk[gbase + kb + 4];
            #pragma unroll
            for (int j = 0; j < 8; ++j) v[j] = (short)f2b((j < 4) ? m0[j] : m1[j - 4]);
        }
        *(s16x8*)&Abuf[(size_t)cc * 8] = v;
    }
    __syncthreads();

    const s16x8* PWf = (const s16x8*)PW;
    const s16x8* PGf = (const s16x8*)PG;

    for (int g = 0; g < 3; ++g) {
        f32x4 acc[4];
        #pragma unroll
        for (int nt = 0; nt < 4; ++nt) acc[nt] = (f32x4)0.f;
        for (int kt = 0; kt < 8; ++kt) {
            s16x8 a = *(const s16x8*)&Abuf[(kt * 64 + L) * 8];
            const s16x8* pw = PWf + ((size_t)(g * 256 + kt * 32 + w * 4) * 64 + L);
            #pragma unroll
            for (int nt = 0; nt < 4; ++nt)
                acc[nt] = __builtin_amdgcn_mfma_f32_16x16x32_bf16(a, pw[(size_t)nt * 64], acc[nt], 0, 0, 0);
        }
        const float* bias = (g == 0) ? bz : (g == 1) ? br : bc;
        bfu* dst = (g == 0) ? pz : (g == 1) ? pr : pc;
        #pragma unroll
        for (int nt = 0; nt < 4; ++nt) {
            int n = w * 64 + nt * 16 + (L & 15);
            float bv = bias[n];
            #pragma unroll
            for (int reg = 0; reg < 4; ++reg) {
                int tl = (L >> 4) * 4 + reg;
                dst[(size_t)(tl * B_ + b) * H_ + n] = f2b(acc[nt][reg] + bv);
            }
        }
    }
    {
        f32x4 acc[4];
        #pragma unroll
        for (int nt = 0; nt < 4; ++nt) acc[nt] = (f32x4)0.f;
        for (int kk = 0; kk < 4; ++kk) {
            s16x8 a = *(const s16x8*)&Abuf[((8 + kk) * 64 + L) * 8];
            const s16x8* pg = PGf + ((size_t)(kk * 32 + w * 4) * 64 + L);
            #pragma unroll
            for (int nt = 0; nt < 4; ++nt)
                acc[nt] = __builtin_amdgcn_mfma_f32_16x16x32_bf16(a, pg[(size_t)nt * 64], acc[nt], 0, 0, 0);
        }
        #pragma unroll
        for (int nt = 0; nt < 4; ++nt) {
            int n = w * 64 + nt * 16 + (L & 15);
            float bv = Bgh[n];
            #pragma unroll
            for (int reg = 0; reg < 4; ++reg) {
                int tl = (L >> 4) * 4 + reg;
                gm[(size_t)(tl * B_ + b) * H_ + n] = f2b(__expf(-fmaxf(acc[nt][reg] + bv, 0.f)));
            }
        }
    }
}

// ===========================================================================
// scan block (pair-split): blocks (p, hb): pair p handles rows [16p,16p+16);
// half hb owns H-columns [hb*256, +256) for z/r (column-split, full K) and
// K-rows [hb*256, +256) for the c GEMM (K-split, all columns).
// wz fp8 slice is VGPR-resident across all 16 steps (FULL unroll in phase A
// so all wzr[] indices are compile-time; (1024,4) gives the 128-VGPR budget).
// Exchange: LDS-staged coalesced u64 export, staged coalesced import (R3).
// ===========================================================================
__device__ void scan_block(char* sm, int p, int hb, int base, const bfu* __restrict__ pre,
                           const short* __restrict__ PUc, const unsigned char* __restrict__ PU8,
                           float* __restrict__ hws,
                           float* __restrict__ zx, float* __restrict__ cx,
                           u32* __restrict__ flags)
{
    char*  Abf8 = sm;                        // 8 KB fp8 A-fragments [16 kt][64][8] (full K)
    short* Apbf = (short*)(sm + 8192);       // 8 KB bf16 (A*r)-fragments, own K-half
    float* rl   = (float*)(sm + 16384);      // 16 KB f32 [16][256]: own r; partner z after import
    float* zl   = (float*)(sm + 32768);      // 16 KB f32 [16][256]: own z
    float* cp   = (float*)(sm + 49152);      // 32 KB f32 [16][512]: own c-partials, then partner's
    const bfu* pz = pre;
    const bfu* pr = pre + SLOTS;
    const bfu* pc = pre + 2 * SLOTS;
    const bfu* gm = pre + 3 * SLOTS;
    const int tid = threadIdx.x, L = tid & 63, w = tid >> 6;
    const int b0 = p * 16;
    const i64* PU8q = (const i64*)PU8;
    const s16x8* PUcf = (const s16x8*)PUc;
    const float INV = 4.8828125e-4f;        // 1/2048

    int nn[2], ktq[2], lsh[2], j2;
    #pragma unroll
    for (int nt = 0; nt < 2; ++nt) {
        nn[nt] = w * 32 + nt * 16 + (L & 15);
        ktq[nt] = nn[nt] >> 5;
        lsh[nt] = ((nn[nt] >> 3) & 3) << 4;
    }
    j2 = nn[0] & 7;
    const int row0 = (L >> 4) * 4;
    const int clzr = w * 16 + (L & 15);      // local col in own 256-slice (z/r mapping)
    const int nzr = hb * 256 + clzr;         // global col (z/r mapping)
    const int ph = w >> 3;                   // half that this wave's nn cols live in

    float* zxO0 = zx + (size_t)(p * 2 + hb) * 2 * 4096;
    float* cxO0 = cx + (size_t)(p * 2 + hb) * 2 * 8192;
    float* zxP0 = zx + (size_t)(p * 2 + (1 - hb)) * 2 * 4096;
    float* cxP0 = cx + (size_t)(p * 2 + (1 - hb)) * 2 * 8192;
    u32* flagO = flags + (size_t)(p * 2 + hb) * 32;
    u32* flagP = flags + (size_t)(p * 2 + (1 - hb)) * 32;

    // ---- wz register-resident across the whole chunk (32 VGPRs).
    //      All uses below are in FULLY unrolled loops (compile-time index)
    //      so this stays in VGPRs under the (1024,4) budget.  ----
    i64 wzr[16];
    #pragma unroll
    for (int kt = 0; kt < 16; ++kt)
        wzr[kt] = PU8q[((size_t)(kt * 32 + hb * 16 + w)) * 64 + L];

    float A32[2][4];
    #pragma unroll
    for (int nt = 0; nt < 2; ++nt)
        #pragma unroll
        for (int reg = 0; reg < 4; ++reg) {
            int row = row0 + reg;
            float h = hws[(size_t)(b0 + row) * H_ + nn[nt]];
            float gv = b2f(gm[(size_t)(b0 + row) * H_ + nn[nt]]);   // tl = 0
            float A = gv * h;
            A32[nt][reg] = A;
            Abf8[(ktq[nt] * 64 + (row | lsh[nt])) * 8 + j2] = f2e4m3(A * 64.f);
        }
    __syncthreads();

    // lpz/lpr for tl=0 (later steps prefetched inside the exchange window)
    float lpzv[4], lprv[4];
    #pragma unroll
    for (int reg = 0; reg < 4; ++reg) {
        int row = b0 + row0 + reg;
        lpzv[reg] = b2f(pz[(size_t)(0 * B_ + row) * H_ + nzr]);
        lprv[reg] = b2f(pr[(size_t)(0 * B_ + row) * H_ + nzr]);
    }

    for (int tl = 0; tl < CH; ++tl) {
        const int S = base + tl;
        const int par = S & 1;
        u64* zxOq = (u64*)(zxO0 + par * 4096);
        u64* cxOq = (u64*)(cxO0 + par * 8192);
        const u64* zxPq = (const u64*)(zxP0 + par * 4096);
        const u64* cxPq = (const u64*)(cxP0 + par * 8192);
        int tln = (tl + 1 < CH) ? tl + 1 : tl;

        // ---- phase A: z/r fp8 GEMMs, own 16 cols per wave, full K ----
        // wz from registers (FULL unroll -> static indices); wr streamed.
        f32x4 az = (f32x4)0.f, ar = (f32x4)0.f;
        #pragma unroll
        for (int kt = 0; kt < 16; ++kt) {
            i64 a8 = *(const i64*)&Abf8[(kt * 64 + L) * 8];
            i64 br8 = PU8q[((size_t)(512 + kt * 32 + hb * 16 + w)) * 64 + L];
            az = __builtin_amdgcn_mfma_f32_16x16x32_fp8_fp8(a8, wzr[kt], az, 0, 0, 0);
            ar = __builtin_amdgcn_mfma_f32_16x16x32_fp8_fp8(a8, br8, ar, 0, 0, 0);
        }
        #pragma unroll
        for (int reg = 0; reg < 4; ++reg) {
            int m = row0 + reg;
            float zg = sigf(az[reg] * INV + lpzv[reg]);
            float rg = sigf(ar[reg] * INV + lprv[reg]);
            zl[m * 256 + clzr] = zg;
            rl[m * 256 + clzr] = rg;
        }
        __syncthreads();   // (1) zl/rl complete

        // ---- export z (coalesced u64), overlaps build + c GEMM ----
        {
            const u64* zlq = (const u64*)zl;
            __hip_atomic_store(&zxOq[tid], zlq[tid], __ATOMIC_RELAXED, __HIP_MEMORY_SCOPE_AGENT);
            __hip_atomic_store(&zxOq[tid + 1024], zlq[tid + 1024], __ATOMIC_RELAXED, __HIP_MEMORY_SCOPE_AGENT);
        }

        // ---- build (A*r) bf16 A-fragments for own K-half ----
        if (ph == hb) {
            #pragma unroll
            for (int nt = 0; nt < 2; ++nt) {
                int kl = nn[nt] & 255;
                int ktql = kl >> 5;
                #pragma unroll
                for (int reg = 0; reg < 4; ++reg) {
                    int m = row0 + reg;
                    Apbf[(ktql * 64 + (m | lsh[nt])) * 8 + j2] = (short)f2b(A32[nt][reg] * rl[m * 256 + kl]);
                }
            }
        }
        __syncthreads();   // (2) Apbf complete

        // ---- c bf16 GEMM: all cols, own K-half ----
        f32x4 ac[2];
        ac[0] = (f32x4)0.f; ac[1] = (f32x4)0.f;
        #pragma unroll 4
        for (int kk = 0; kk < 8; ++kk) {
            s16x8 a = *(const s16x8*)&Apbf[(kk * 64 + L) * 8];
            const s16x8* c8 = PUcf + ((size_t)((hb * 8 + kk) * 32 + w * 2) * 64 + L);
            s16x8 bc0 = c8[0], bc1 = c8[64];
            ac[0] = __builtin_amdgcn_mfma_f32_16x16x32_bf16(a, bc0, ac[0], 0, 0, 0);
            ac[1] = __builtin_amdgcn_mfma_f32_16x16x32_bf16(a, bc1, ac[1], 0, 0, 0);
        }
        #pragma unroll
        for (int nt = 0; nt < 2; ++nt)
            #pragma unroll
            for (int reg = 0; reg < 4; ++reg)
                cp[(row0 + reg) * 512 + nn[nt]] = ac[nt][reg];
        __syncthreads();   // (3) cp complete

        // ---- export c-partials (coalesced u64) ----
        {
            const u64* cpq = (const u64*)cp;
            #pragma unroll
            for (int i = 0; i < 4; ++i)
                __hip_atomic_store(&cxOq[tid + i * 1024], cpq[tid + i * 1024],
                                   __ATOMIC_RELAXED, __HIP_MEMORY_SCOPE_AGENT);
        }
        __syncthreads();   // (4) all waves' exports drained (vmcnt 0 before barrier)
        if (tid == 0)
            __hip_atomic_store(flagO, (u32)(S + 1), __ATOMIC_RELEASE, __HIP_MEMORY_SCOPE_AGENT);

        // ---- prefetch update operands (this tl) + lpz/lpr (next tl);
        //      latency hides under partner round-trip ----
        float lpcv[2][4], lgmv[2][4];
        #pragma unroll
        for (int nt = 0; nt < 2; ++nt)
            #pragma unroll
            for (int reg = 0; reg < 4; ++reg) {
                int row = b0 + row0 + reg;
                lpcv[nt][reg] = b2f(pc[(size_t)(tl * B_ + row) * H_ + nn[nt]]);
                lgmv[nt][reg] = b2f(gm[(size_t)(tln * B_ + row) * H_ + nn[nt]]);
            }
        #pragma unroll
        for (int reg = 0; reg < 4; ++reg) {
            int row = b0 + row0 + reg;
            lpzv[reg] = b2f(pz[(size_t)(tln * B_ + row) * H_ + nzr]);
            lprv[reg] = b2f(pr[(size_t)(tln * B_ + row) * H_ + nzr]);
        }

        if (tid == 0) {
            while (__hip_atomic_load(flagP, __ATOMIC_RELAXED, __HIP_MEMORY_SCOPE_AGENT) < (u32)(S + 1))
                __builtin_amdgcn_s_sleep(1);
        }
        __syncthreads();   // (5) partner data ready

        // ---- import partner z -> rl space, partner c-partials -> cp ----
        {
            u64* cpdq = (u64*)cp;
            u64* zlPq = (u64*)rl;
            #pragma unroll
            for (int i = 0; i < 4; ++i)
                cpdq[tid + i * 1024] = __hip_atomic_load(&cxPq[tid + i * 1024],
                                                         __ATOMIC_RELAXED, __HIP_MEMORY_SCOPE_AGENT);
            #pragma unroll
            for (int i = 0; i < 2; ++i)
                zlPq[tid + i * 1024] = __hip_atomic_load(&zxPq[tid + i * 1024],
                                                         __ATOMIC_RELAXED, __HIP_MEMORY_SCOPE_AGENT);
        }
        __syncthreads();   // (6) import staged

        // ---- state update (all cols, duplicated across the pair) ----
        #pragma unroll
        for (int nt = 0; nt < 2; ++nt) {
            int kl = nn[nt] & 255;
            #pragma unroll
            for (int reg = 0; reg < 4; ++reg) {
                int m = row0 + reg;
                float zg = (ph == hb) ? zl[m * 256 + kl] : rl[m * 256 + kl];
                float cpe = cp[m * 512 + nn[nt]];
                float cc = tanhfast(ac[nt][reg] + cpe + lpcv[nt][reg]);
                float hn = (1.f - zg) * A32[nt][reg] + zg * cc;
                if (tl < CH - 1) {
                    float An = lgmv[nt][reg] * hn;
                    A32[nt][reg] = An;
                    Abf8[(ktq[nt] * 64 + (m | lsh[nt])) * 8 + j2] = f2e4m3(An * 64.f);
                } else if (ph == hb) {
                    hws[(size_t)(b0 + m) * H_ + nn[nt]] = hn;
                }
            }
        }
        __syncthreads();   // (7) Abf8/zl/rl safe to overwrite next step
    }
}

// ===========================================================================
// fused launch: blocks 0-31 scan chunk c-1 (16 pairs x 2 halves);
// blocks 32-159 (2x512-thr units) compute pre-activations for chunk c.
// ===========================================================================
__global__ __launch_bounds__(1024, 4) void k_fused(int c,
    const float* __restrict__ x, const float* __restrict__ dl,
    const float* __restrict__ mk, const float* __restrict__ xf,
    const float* __restrict__ bz, const float* __restrict__ br, const float* __restrict__ bc,
    const float* __restrict__ Bgh,
    const float* __restrict__ Wgx, const float* __restrict__ Bgx,
    const short* __restrict__ PW, const short* __restrict__ PG,
    const short* __restrict__ PUc, const unsigned char* __restrict__ PU8,
    bfu* __restrict__ buf0, bfu* __restrict__ buf1, float* __restrict__ hws,
    float* __restrict__ zx, float* __restrict__ cx, u32* __restrict__ flags)
{
    __shared__ char sm[81920];
    if (blockIdx.x < 32) {
        if (c == 0) return;
        const bfu* pre = (c & 1) ? buf0 : buf1;    // chunk c-1 lives in buf[(c-1)&1]
        int p = blockIdx.x & 15, hb = blockIdx.x >> 4;
        scan_block(sm, p, hb, (c - 1) * CH, pre, PUc, PU8, hws, zx, cx, flags);
    } else {
        if (c >= NCH) return;
        int unit = ((int)blockIdx.x - 32) * 2 + (threadIdx.x >> 9);
        if (unit >= B_) return;
        bfu* dst = (c & 1) ? buf1 : buf0;           // chunk c -> buf[c&1]
        k1_unit(sm + (threadIdx.x >> 9) * 12288, unit, c * CH,
                x, dl, mk, xf, bz, br, bc, Bgh, Wgx, Bgx, PW, PG,
                dst, dst + SLOTS, dst + 2 * SLOTS, dst + 3 * SLOTS);
    }
}

// ===========================================================================
// k3: BatchNorm(eval) + decoder GEMV + log_softmax.
// ===========================================================================
__global__ __launch_bounds__(128) void k3_out(
    const float* __restrict__ hws,
    const float* __restrict__ dW, const float* __restrict__ db,
    const float* __restrict__ bng, const float* __restrict__ bnb,
    float* __restrict__ out)
{
    __shared__ float hb[H_];
    __shared__ float red[O_];
    const int tid = threadIdx.x;
    const int b = blockIdx.x;
    const float s = 0.9999950000374997f;   // 1/sqrt(1 + 1e-5)
    for (int k = tid; k < H_; k += O_) {
        float v = hws[(size_t)b * H_ + k] * s * bng[k] + bnb[k];
        hb[k] = v;
        out[B_ * O_ + (size_t)b * H_ + k] = v;
    }
    __syncthreads();
    float acc = db[tid];
    #pragma unroll 4
    for (int k = 0; k < H_; ++k) acc += hb[k] * dW[(size_t)k * O_ + tid];
    red[tid] = acc;
    __syncthreads();
    for (int sh = 64; sh > 0; sh >>= 1) {
        if (tid < sh) red[tid] = fmaxf(red[tid], red[tid + sh]);
        __syncthreads();
    }
    float mx = red[0];
    __syncthreads();
    red[tid] = __expf(acc - mx);
    __syncthreads();
    for (int sh = 64; sh > 0; sh >>= 1) {
        if (tid < sh) red[tid] += red[tid + sh];
        __syncthreads();
    }
    float lse = __logf(red[0]) + mx;
    out[(size_t)b * O_ + tid] = acc - lse;
}

extern "C" void kernel_launch(void* const* d_in, const int* in_sizes, int n_in,
                              void* d_out, int out_size, void* d_ws, size_t ws_size,
                              hipStream_t stream)
{
    (void)in_sizes; (void)n_in; (void)out_size; (void)ws_size;
    const float* x   = (const float*)d_in[0];
    const float* dl  = (const float*)d_in[1];
    const float* m   = (const float*)d_in[2];
    const float* xf  = (const float*)d_in[3];
    const float* Wr  = (const float*)d_in[4];
    const float* Ur  = (const float*)d_in[5];
    const float* Vr  = (const float*)d_in[6];
    const float* br  = (const float*)d_in[7];
    const float* Wz  = (const float*)d_in[8];
    const float* Uz  = (const float*)d_in[9];
    const float* Vz  = (const float*)d_in[10];
    const float* bz  = (const float*)d_in[11];
    const float* Wc  = (const float*)d_in[12];
    const float* Uc  = (const float*)d_in[13];
    const float* Vc  = (const float*)d_in[14];
    const float* bc  = (const float*)d_in[15];
    const float* Wgx = (const float*)d_in[16];
    const float* Bgx = (const float*)d_in[17];
    const float* Wgh = (const float*)d_in[18];
    const float* Bgh = (const float*)d_in[19];
    const float* dW  = (const float*)d_in[20];
    const float* db  = (const float*)d_in[21];
    const float* bng = (const float*)d_in[22];
    const float* bnb = (const float*)d_in[23];

    char* p = (char*)d_ws;
    short* PW = (short*)p;              p += (size_t)3 * 256 * 64 * 8 * 2;   // 768 KB
    short* PG = (short*)p;              p += (size_t)128 * 64 * 8 * 2;       // 128 KB
    short* PUc = (short*)p;             p += (size_t)512 * 64 * 8 * 2;       // 512 KB
    unsigned char* PU8 = (unsigned char*)p; p += (size_t)1024 * 64 * 8;      // 512 KB
    bfu* buf0 = (bfu*)p;                p += 4 * SLOTS * 2;                  // 16 MB
    bfu* buf1 = (bfu*)p;                p += 4 * SLOTS * 2;                  // 16 MB
    float* hws = (float*)p;             p += (size_t)B_ * H_ * 4;            // 512 KB
    float* zx  = (float*)p;             p += (size_t)16 * 2 * 2 * 4096 * 4;  // 1 MB
    float* cx  = (float*)p;             p += (size_t)16 * 2 * 2 * 8192 * 4;  // 2 MB
    u32* flags = (u32*)p;                                                    // 4 KB

    hipMemsetAsync(hws, 0, (size_t)B_ * H_ * sizeof(float), stream);
    hipMemsetAsync(flags, 0, (size_t)32 * 32 * sizeof(u32), stream);
    k_pack<<<dim3(608), dim3(256), 0, stream>>>(Wz, Wr, Wc, Vz, Vr, Vc, Wgh,
                                                Uz, Ur, Uc, PW, PG, PUc, PU8);
    for (int c = 0; c <= NCH; ++c) {
        k_fused<<<dim3(160), dim3(1024), 0, stream>>>(c,
            x, dl, m, xf, bz, br, bc, Bgh, Wgx, Bgx,
            PW, PG, PUc, PU8, buf0, buf1, hws, zx, cx, flags);
    }
    k3_out<<<dim3(B_), dim3(O_), 0, stream>>>(hws, dW, db, bng, bnb, (float*)d_out);
}

// Round 6
// 3486.510 us; speedup vs baseline: 1.3161x; 1.1076x over previous
//
#include <hip/hip_runtime.h>
#include <stdint.h>

typedef float  f32x4 __attribute__((ext_vector_type(4)));
typedef short  s16x8 __attribute__((ext_vector_type(8)));
typedef unsigned int u32;
typedef unsigned long long u64;
typedef unsigned short bfu;
typedef long long i64;

#define B_ 256
#define T_ 256
#define I_ 128
#define H_ 512
#define O_ 128
#define CH 16
#define NCH (T_ / CH)
#define SLOTS ((size_t)CH * B_ * H_)   // elems per bf16 pre-array

__device__ __forceinline__ bfu f2b(float f) {
    u32 u = __float_as_uint(f);
    u += 0x7fffu + ((u >> 16) & 1u);
    return (bfu)(u >> 16);
}
__device__ __forceinline__ float b2f(bfu b) { return __uint_as_float(((u32)b) << 16); }
__device__ __forceinline__ float sigf(float x) { return 1.f / (1.f + __expf(-x)); }
__device__ __forceinline__ float tanhfast(float x) { return 1.f - 2.f / (__expf(2.f * x) + 1.f); }
__device__ __forceinline__ u64 pk2(float a, float b) {
    return (u64)__float_as_uint(a) | ((u64)__float_as_uint(b) << 32);
}
__device__ __forceinline__ float lo2(u64 v) { return __uint_as_float((u32)v); }
__device__ __forceinline__ float hi2(u64 v) { return __uint_as_float((u32)(v >> 32)); }

// software float -> OCP e4m3fn, RNE, saturating
__device__ __forceinline__ unsigned char f2e4m3(float f) {
    u32 u = __float_as_uint(f);
    u32 s = (u >> 24) & 0x80u;
    u &= 0x7fffffffu;
    if (u >= 0x43e00000u) return (unsigned char)(s | 0x7eu);    // >= 448 -> sat
    if (u < 0x3c800000u) {                                       // < 2^-6 -> subnormal
        int m = __float2int_rn(__uint_as_float(u) * 512.f);
        if (m >= 8) return (unsigned char)(s | 0x08u);
        return (unsigned char)(s | (u32)m);
    }
    u += 0x7ffffu + ((u >> 20) & 1u);                            // RNE at bit 20
    u32 e8 = ((u >> 23) & 0xffu) - 120u;                         // bias 127 -> 7
    return (unsigned char)(s | (e8 << 3) | ((u >> 20) & 7u));
}

// ===========================================================================
// k_pack: weights -> MFMA B-fragment order.
// frag 16x16x32: lane L holds B[k = kt*32 + (L>>4)*8 + j][n = nt*16 + (L&15)].
// PW bf16 (W|V per gate), PG bf16 (Wgh), PUc bf16 (Uc), PU8 fp8 (Uz,Ur x32).
// ===========================================================================
__global__ __launch_bounds__(256) void k_pack(
    const float* __restrict__ Wz, const float* __restrict__ Wr, const float* __restrict__ Wc,
    const float* __restrict__ Vz, const float* __restrict__ Vr, const float* __restrict__ Vc,
    const float* __restrict__ Wgh,
    const float* __restrict__ Uz, const float* __restrict__ Ur, const float* __restrict__ Uc,
    short* __restrict__ PW, short* __restrict__ PG, short* __restrict__ PUc,
    unsigned char* __restrict__ PU8)
{
    int wv = blockIdx.x * 4 + (threadIdx.x >> 6);
    int L = threadIdx.x & 63;
    if (wv >= 2432) return;
    int koff = (L >> 4) << 3;
    int ncol;
    if (wv < 768) {                       // PW: gate x (kt<4:W, kt>=4:V)
        int g = wv >> 8, rem = wv & 255;
        int kt = rem >> 5; ncol = (rem & 31) * 16 + (L & 15);
        const float* src = (kt < 4) ? (g == 0 ? Wz : g == 1 ? Wr : Wc)
                                    : (g == 0 ? Vz : g == 1 ? Vr : Vc);
        int kbase = (kt & 3) * 32 + koff;
        s16x8 v;
        #pragma unroll
        for (int j = 0; j < 8; ++j) v[j] = (short)f2b(src[(kbase + j) * H_ + ncol]);
        *(s16x8*)&PW[((size_t)(g * 256 + rem) * 64 + L) * 8] = v;
    } else if (wv < 896) {                // PG
        int rem = wv - 768;
        ncol = (rem & 31) * 16 + (L & 15);
        int kbase = (rem >> 5) * 32 + koff;
        s16x8 v;
        #pragma unroll
        for (int j = 0; j < 8; ++j) v[j] = (short)f2b(Wgh[(kbase + j) * H_ + ncol]);
        *(s16x8*)&PG[((size_t)rem * 64 + L) * 8] = v;
    } else if (wv < 1408) {               // PUc bf16
        int rem = wv - 896;               // kt*32+nt, kt 0..15
        ncol = (rem & 31) * 16 + (L & 15);
        int kbase = (rem >> 5) * 32 + koff;
        s16x8 v;
        #pragma unroll
        for (int j = 0; j < 8; ++j) v[j] = (short)f2b(Uc[(kbase + j) * H_ + ncol]);
        *(s16x8*)&PUc[((size_t)rem * 64 + L) * 8] = v;
    } else {                              // PU8: Uz, Ur scaled x32, e4m3
        int rem = wv - 1408;              // g*512 + kt*32 + nt
        int g = rem >> 9, r2 = rem & 511;
        ncol = (r2 & 31) * 16 + (L & 15);
        int kbase = (r2 >> 5) * 32 + koff;
        const float* src = (g == 0) ? Uz : Ur;
        unsigned char* d = PU8 + ((size_t)rem * 64 + L) * 8;
        #pragma unroll
        for (int j = 0; j < 8; ++j) d[j] = f2e4m3(src[(kbase + j) * H_ + ncol] * 32.f);
    }
}

// ===========================================================================
// k1 unit: input-side projections for one batch row b, 16 timesteps.
// 512 threads (8 waves x 64 cols). bf16 outputs, layout [tl][b][H].
// ===========================================================================
__device__ void k1_unit(char* sm, int b, int t0,
    const float* __restrict__ x, const float* __restrict__ dl,
    const float* __restrict__ mk, const float* __restrict__ xf,
    const float* __restrict__ bz, const float* __restrict__ br, const float* __restrict__ bc,
    const float* __restrict__ Bgh,
    const float* __restrict__ Wgx, const float* __restrict__ Bgx,
    const short* __restrict__ PW, const short* __restrict__ PG,
    bfu* __restrict__ pz, bfu* __restrict__ pr, bfu* __restrict__ pc, bfu* __restrict__ gm)
{
    short* Abuf = (short*)sm;             // 12 KB: [kt 0..11][lane][8]
    const int t = threadIdx.x & 511;
    const int L = t & 63, w = t >> 6;

    for (int cc = t; cc < 12 * 64; cc += 512) {
        int Ls = cc & 63, kt = cc >> 6;
        int tl = Ls & 15, q = Ls >> 4;
        int gbase = (b * T_ + t0 + tl) * I_;
        s16x8 v;
        if (kt < 4) {
            int kb = kt * 32 + q * 8;
            f32x4 m0 = *(const f32x4*)&mk[gbase + kb], m1 = *(const f32x4*)&mk[gbase + kb + 4];
            f32x4 d0 = *(const f32x4*)&dl[gbase + kb], d1 = *(const f32x4*)&dl[gbase + kb + 4];
            f32x4 f0 = *(const f32x4*)&xf[gbase + kb], f1 = *(const f32x4*)&xf[gbase + kb + 4];
            f32x4 x0 = *(const f32x4*)&x[gbase + kb],  x1 = *(const f32x4*)&x[gbase + kb + 4];
            #pragma unroll
            for (int j = 0; j < 8; ++j) {
                int k = kb + j;
                float mv = (j < 4) ? m0[j] : m1[j - 4];
                float dv = (j < 4) ? d0[j] : d1[j - 4];
                float fv = (j < 4) ? f0[j] : f1[j - 4];
                float xv = (j < 4) ? x0[j] : x1[j - 4];
                float dx = dv * Wgx[k] + Bgx[k];
                float xr = dx * fv + (1.f - dx) * 0.001f;
                v[j] = (short)f2b((mv > 0.5f) ? xr : xv);
            }
        } else if (kt < 8) {
            int kb = (kt - 4) * 32 + q * 8;
            f32x4 m0 = *(const f32x4*)&mk[gbase + kb], m1 = *(const f32x4*)&mk[gbase + kb + 4];
            #pragma unroll
            for (int j = 0; j < 8; ++j) v[j] = (short)f2b(1.f - ((j < 4) ? m0[j] : m1[j - 4]));
        } else {
            int kb = (kt - 8) * 32 + q * 8;
            f32x4 m0 = *(const f32x4*)&mk[gbase + kb], m1 = *(const f32x4*)&mk[gbase + kb + 4];
            #pragma unroll
            for (int j = 0; j < 8; ++j) v[j] = (short)f2b((j < 4) ? m0[j] : m1[j - 4]);
        }
        *(s16x8*)&Abuf[(size_t)cc * 8] = v;
    }
    __syncthreads();

    const s16x8* PWf = (const s16x8*)PW;
    const s16x8* PGf = (const s16x8*)PG;

    for (int g = 0; g < 3; ++g) {
        f32x4 acc[4];
        #pragma unroll
        for (int nt = 0; nt < 4; ++nt) acc[nt] = (f32x4)0.f;
        for (int kt = 0; kt < 8; ++kt) {
            s16x8 a = *(const s16x8*)&Abuf[(kt * 64 + L) * 8];
            const s16x8* pw = PWf + ((size_t)(g * 256 + kt * 32 + w * 4) * 64 + L);
            #pragma unroll
            for (int nt = 0; nt < 4; ++nt)
                acc[nt] = __builtin_amdgcn_mfma_f32_16x16x32_bf16(a, pw[(size_t)nt * 64], acc[nt], 0, 0, 0);
        }
        const float* bias = (g == 0) ? bz : (g == 1) ? br : bc;
        bfu* dst = (g == 0) ? pz : (g == 1) ? pr : pc;
        #pragma unroll
        for (int nt = 0; nt < 4; ++nt) {
            int n = w * 64 + nt * 16 + (L & 15);
            float bv = bias[n];
            #pragma unroll
            for (int reg = 0; reg < 4; ++reg) {
                int tl = (L >> 4) * 4 + reg;
                dst[(size_t)(tl * B_ + b) * H_ + n] = f2b(acc[nt][reg] + bv);
            }
        }
    }
    {
        f32x4 acc[4];
        #pragma unroll
        for (int nt = 0; nt < 4; ++nt) acc[nt] = (f32x4)0.f;
        for (int kk = 0; kk < 4; ++kk) {
            s16x8 a = *(const s16x8*)&Abuf[((8 + kk) * 64 + L) * 8];
            const s16x8* pg = PGf + ((size_t)(kk * 32 + w * 4) * 64 + L);
            #pragma unroll
            for (int nt = 0; nt < 4; ++nt)
                acc[nt] = __builtin_amdgcn_mfma_f32_16x16x32_bf16(a, pg[(size_t)nt * 64], acc[nt], 0, 0, 0);
        }
        #pragma unroll
        for (int nt = 0; nt < 4; ++nt) {
            int n = w * 64 + nt * 16 + (L & 15);
            float bv = Bgh[n];
            #pragma unroll
            for (int reg = 0; reg < 4; ++reg) {
                int tl = (L >> 4) * 4 + reg;
                gm[(size_t)(tl * B_ + b) * H_ + n] = f2b(__expf(-fmaxf(acc[nt][reg] + bv, 0.f)));
            }
        }
    }
}

// ===========================================================================
// scan block (pair-split, R6 restructure): pair p rows [16p,16p+16); half hb
// owns z/r cols [hb*256,+256) and c-GEMM K-rows [hb*256,+256).
// Phase A split by wave group: waves with ph!=hb compute z-tiles (own-half
// cols) -> zl LDS + direct col-major export; waves with ph==hb compute
// r-tiles at their OWN nn cols and fold the (A*r) build into phase A
// (r never touches LDS). c-partials exported direct from registers in
// col-major layout (16-B contiguous per thread). 4 barriers/step.
// ===========================================================================
__device__ void scan_block(char* sm, int p, int hb, int base, const bfu* __restrict__ pre,
                           const short* __restrict__ PUc, const unsigned char* __restrict__ PU8,
                           float* __restrict__ hws,
                           float* __restrict__ zx, float* __restrict__ cx,
                           u32* __restrict__ flags)
{
    char*  Abf8 = sm;                        // 8 KB fp8 A-fragments [16 kt][64][8] (full K)
    short* Apbf = (short*)(sm + 8192);       // 8 KB bf16 (A*r)-fragments, own K-half
    float* zl   = (float*)(sm + 16384);      // 16 KB f32 col-major [256 cols][16 rows]: own z
    const bfu* pz = pre;
    const bfu* pr = pre + SLOTS;
    const bfu* pc = pre + 2 * SLOTS;
    const bfu* gm = pre + 3 * SLOTS;
    const int tid = threadIdx.x, L = tid & 63, w = tid >> 6;
    const int b0 = p * 16;
    const i64* PU8q = (const i64*)PU8;
    const s16x8* PUcf = (const s16x8*)PUc;
    const float INV = 4.8828125e-4f;        // 1/2048

    int nn[2], ktq[2], lsh[2], j2;
    #pragma unroll
    for (int nt = 0; nt < 2; ++nt) {
        nn[nt] = w * 32 + nt * 16 + (L & 15);
        ktq[nt] = nn[nt] >> 5;
        lsh[nt] = ((nn[nt] >> 3) & 3) << 4;
    }
    j2 = nn[0] & 7;
    const int row0 = (L >> 4) * 4;
    const int ph = w >> 3;                   // half that this wave's nn cols live in
    const bool isR = (ph == hb);             // r/build wave group
    // local col (within own 256-slice) of this wave's 2 tiles
    int lc[2];
    #pragma unroll
    for (int nt = 0; nt < 2; ++nt) lc[nt] = nn[nt] & 255;
    // phase-A column indices: z/r both computed at own-half cols hb*256+lc
    int pa_col[2];
    #pragma unroll
    for (int nt = 0; nt < 2; ++nt) pa_col[nt] = hb * 256 + lc[nt];
    // weight tile base in PU8: z tiles for A-group, r tiles (+512) for B-group
    const int tbase = (isR ? 512 : 0) + hb * 16 + (w & 7) * 2;

    float* zxO0 = zx + (size_t)(p * 2 + hb) * 2 * 4096;
    float* cxO0 = cx + (size_t)(p * 2 + hb) * 2 * 8192;
    float* zxP0 = zx + (size_t)(p * 2 + (1 - hb)) * 2 * 4096;
    float* cxP0 = cx + (size_t)(p * 2 + (1 - hb)) * 2 * 8192;
    u32* flagO = flags + (size_t)(p * 2 + hb) * 32;
    u32* flagP = flags + (size_t)(p * 2 + (1 - hb)) * 32;

    float A32[2][4];
    #pragma unroll
    for (int nt = 0; nt < 2; ++nt)
        #pragma unroll
        for (int reg = 0; reg < 4; ++reg) {
            int row = row0 + reg;
            float h = hws[(size_t)(b0 + row) * H_ + nn[nt]];
            float gv = b2f(gm[(size_t)(b0 + row) * H_ + nn[nt]]);   // tl = 0
            float A = gv * h;
            A32[nt][reg] = A;
            Abf8[(ktq[nt] * 64 + (row | lsh[nt])) * 8 + j2] = f2e4m3(A * 64.f);
        }
    __syncthreads();

    // phase-A pre-activations for tl=0 (later steps prefetched in the window)
    float lpa[2][4];       // lpz (A-group at pa_col) or lpr (B-group at nn)
    {
        const bfu* src = isR ? pr : pz;
        #pragma unroll
        for (int nt = 0; nt < 2; ++nt)
            #pragma unroll
            for (int reg = 0; reg < 4; ++reg)
                lpa[nt][reg] = b2f(src[(size_t)(0 * B_ + b0 + row0 + reg) * H_ + pa_col[nt]]);
    }

    for (int tl = 0; tl < CH; ++tl) {
        const int S = base + tl;
        const int par = S & 1;
        u64* zxOq = (u64*)(zxO0 + par * 4096);
        u64* cxOq = (u64*)(cxO0 + par * 8192);
        const u64* zxPq = (const u64*)(zxP0 + par * 4096);
        const u64* cxPq = (const u64*)(cxP0 + par * 8192);
        int tln = (tl + 1 < CH) ? tl + 1 : tl;

        // ---- phase A: fp8 GEMM, 2 tiles/wave (z for A-group, r for B-group) ----
        f32x4 a0 = (f32x4)0.f, a1 = (f32x4)0.f;
        #pragma unroll 4
        for (int kt = 0; kt < 16; ++kt) {
            i64 a8 = *(const i64*)&Abf8[(kt * 64 + L) * 8];
            i64 w0 = PU8q[((size_t)(kt * 32 + tbase)) * 64 + L];
            i64 w1 = PU8q[((size_t)(kt * 32 + tbase + 1)) * 64 + L];
            a0 = __builtin_amdgcn_mfma_f32_16x16x32_fp8_fp8(a8, w0, a0, 0, 0, 0);
            a1 = __builtin_amdgcn_mfma_f32_16x16x32_fp8_fp8(a8, w1, a1, 0, 0, 0);
        }
        if (isR) {
            // r in registers -> fold the (A*r) build directly into phase A
            #pragma unroll
            for (int reg = 0; reg < 4; ++reg) {
                float rg0 = sigf(a0[reg] * INV + lpa[0][reg]);
                float rg1 = sigf(a1[reg] * INV + lpa[1][reg]);
                int m = row0 + reg;
                Apbf[((lc[0] >> 5) * 64 + (m | lsh[0])) * 8 + j2] = (short)f2b(A32[0][reg] * rg0);
                Apbf[((lc[1] >> 5) * 64 + (m | lsh[1])) * 8 + j2] = (short)f2b(A32[1][reg] * rg1);
            }
        } else {
            // z -> zl LDS (col-major) + direct export (col-major, coalesced)
            f32x4 zq0, zq1;
            #pragma unroll
            for (int reg = 0; reg < 4; ++reg) {
                zq0[reg] = sigf(a0[reg] * INV + lpa[0][reg]);
                zq1[reg] = sigf(a1[reg] * INV + lpa[1][reg]);
            }
            *(f32x4*)&zl[lc[0] * 16 + row0] = zq0;
            *(f32x4*)&zl[lc[1] * 16 + row0] = zq1;
            int i0 = (lc[0] * 16 + row0) >> 1, i1 = (lc[1] * 16 + row0) >> 1;
            __hip_atomic_store(&zxOq[i0],     pk2(zq0[0], zq0[1]), __ATOMIC_RELAXED, __HIP_MEMORY_SCOPE_AGENT);
            __hip_atomic_store(&zxOq[i0 + 1], pk2(zq0[2], zq0[3]), __ATOMIC_RELAXED, __HIP_MEMORY_SCOPE_AGENT);
            __hip_atomic_store(&zxOq[i1],     pk2(zq1[0], zq1[1]), __ATOMIC_RELAXED, __HIP_MEMORY_SCOPE_AGENT);
            __hip_atomic_store(&zxOq[i1 + 1], pk2(zq1[2], zq1[3]), __ATOMIC_RELAXED, __HIP_MEMORY_SCOPE_AGENT);
        }
        __syncthreads();   // (1) Apbf + zl ready (z exports drained here too)

        // ---- c bf16 GEMM: all cols, own K-half ----
        f32x4 ac[2];
        ac[0] = (f32x4)0.f; ac[1] = (f32x4)0.f;
        #pragma unroll 4
        for (int kk = 0; kk < 8; ++kk) {
            s16x8 a = *(const s16x8*)&Apbf[(kk * 64 + L) * 8];
            const s16x8* c8 = PUcf + ((size_t)((hb * 8 + kk) * 32 + w * 2) * 64 + L);
            s16x8 bc0 = c8[0], bc1 = c8[64];
            ac[0] = __builtin_amdgcn_mfma_f32_16x16x32_bf16(a, bc0, ac[0], 0, 0, 0);
            ac[1] = __builtin_amdgcn_mfma_f32_16x16x32_bf16(a, bc1, ac[1], 0, 0, 0);
        }
        // direct col-major export of c-partials (2 u64 per tile, coalesced)
        #pragma unroll
        for (int nt = 0; nt < 2; ++nt) {
            int ix = (nn[nt] * 16 + row0) >> 1;
            __hip_atomic_store(&cxOq[ix],     pk2(ac[nt][0], ac[nt][1]), __ATOMIC_RELAXED, __HIP_MEMORY_SCOPE_AGENT);
            __hip_atomic_store(&cxOq[ix + 1], pk2(ac[nt][2], ac[nt][3]), __ATOMIC_RELAXED, __HIP_MEMORY_SCOPE_AGENT);
        }
        __syncthreads();   // (2) all waves' exports drained (vmcnt 0 before barrier)
        if (tid == 0)
            __hip_atomic_store(flagO, (u32)(S + 1), __ATOMIC_RELEASE, __HIP_MEMORY_SCOPE_AGENT);

        // ---- prefetch update operands (this tl) + phase-A preacts (next tl);
        //      latency hides under partner round-trip ----
        float lpcv[2][4], lgmv[2][4];
        #pragma unroll
        for (int nt = 0; nt < 2; ++nt)
            #pragma unroll
            for (int reg = 0; reg < 4; ++reg) {
                int row = b0 + row0 + reg;
                lpcv[nt][reg] = b2f(pc[(size_t)(tl * B_ + row) * H_ + nn[nt]]);
                lgmv[nt][reg] = b2f(gm[(size_t)(tln * B_ + row) * H_ + nn[nt]]);
            }
        {
            const bfu* src = isR ? pr : pz;
            #pragma unroll
            for (int nt = 0; nt < 2; ++nt)
                #pragma unroll
                for (int reg = 0; reg < 4; ++reg)
                    lpa[nt][reg] = b2f(src[(size_t)(tln * B_ + b0 + row0 + reg) * H_ + pa_col[nt]]);
        }

        if (tid == 0) {
            while (__hip_atomic_load(flagP, __ATOMIC_RELAXED, __HIP_MEMORY_SCOPE_AGENT) < (u32)(S + 1))
                __builtin_amdgcn_s_sleep(1);
        }
        __syncthreads();   // (3) partner data ready

        // ---- import direct to registers + state update ----
        #pragma unroll
        for (int nt = 0; nt < 2; ++nt) {
            int ix = (nn[nt] * 16 + row0) >> 1;
            u64 c0 = __hip_atomic_load(&cxPq[ix],     __ATOMIC_RELAXED, __HIP_MEMORY_SCOPE_AGENT);
            u64 c1 = __hip_atomic_load(&cxPq[ix + 1], __ATOMIC_RELAXED, __HIP_MEMORY_SCOPE_AGENT);
            float cpe[4] = { lo2(c0), hi2(c0), lo2(c1), hi2(c1) };
            float zg[4];
            if (isR) {
                f32x4 zv = *(const f32x4*)&zl[lc[nt] * 16 + row0];
                zg[0] = zv[0]; zg[1] = zv[1]; zg[2] = zv[2]; zg[3] = zv[3];
            } else {
                int iz = (lc[nt] * 16 + row0) >> 1;
                u64 z0 = __hip_atomic_load(&zxPq[iz],     __ATOMIC_RELAXED, __HIP_MEMORY_SCOPE_AGENT);
                u64 z1 = __hip_atomic_load(&zxPq[iz + 1], __ATOMIC_RELAXED, __HIP_MEMORY_SCOPE_AGENT);
                zg[0] = lo2(z0); zg[1] = hi2(z0); zg[2] = lo2(z1); zg[3] = hi2(z1);
            }
            #pragma unroll
            for (int reg = 0; reg < 4; ++reg) {
                int m = row0 + reg;
                float cc = tanhfast(ac[nt][reg] + cpe[reg] + lpcv[nt][reg]);
                float hn = (1.f - zg[reg]) * A32[nt][reg] + zg[reg] * cc;
                if (tl < CH - 1) {
                    float An = lgmv[nt][reg] * hn;
                    A32[nt][reg] = An;
                    Abf8[(ktq[nt] * 64 + (m | lsh[nt])) * 8 + j2] = f2e4m3(An * 64.f);
                } else if (isR) {
                    hws[(size_t)(b0 + m) * H_ + nn[nt]] = hn;
                }
            }
        }
        __syncthreads();   // (4) Abf8/zl/Apbf safe to overwrite next step
    }
}

// ===========================================================================
// fused launch: blocks 0-31 scan chunk c-1 (16 pairs x 2 halves);
// blocks 32-159 (2x512-thr units) compute pre-activations for chunk c.
// ===========================================================================
__global__ __launch_bounds__(1024) void k_fused(int c,
    const float* __restrict__ x, const float* __restrict__ dl,
    const float* __restrict__ mk, const float* __restrict__ xf,
    const float* __restrict__ bz, const float* __restrict__ br, const float* __restrict__ bc,
    const float* __restrict__ Bgh,
    const float* __restrict__ Wgx, const float* __restrict__ Bgx,
    const short* __restrict__ PW, const short* __restrict__ PG,
    const short* __restrict__ PUc, const unsigned char* __restrict__ PU8,
    bfu* __restrict__ buf0, bfu* __restrict__ buf1, float* __restrict__ hws,
    float* __restrict__ zx, float* __restrict__ cx, u32* __restrict__ flags)
{
    __shared__ char sm[32768];
    if (blockIdx.x < 32) {
        if (c == 0) return;
        const bfu* pre = (c & 1) ? buf0 : buf1;    // chunk c-1 lives in buf[(c-1)&1]
        int p = blockIdx.x & 15, hb = blockIdx.x >> 4;
        scan_block(sm, p, hb, (c - 1) * CH, pre, PUc, PU8, hws, zx, cx, flags);
    } else {
        if (c >= NCH) return;
        int unit = ((int)blockIdx.x - 32) * 2 + (threadIdx.x >> 9);
        if (unit >= B_) return;
        bfu* dst = (c & 1) ? buf1 : buf0;           // chunk c -> buf[c&1]
        k1_unit(sm + (threadIdx.x >> 9) * 12288, unit, c * CH,
                x, dl, mk, xf, bz, br, bc, Bgh, Wgx, Bgx, PW, PG,
                dst, dst + SLOTS, dst + 2 * SLOTS, dst + 3 * SLOTS);
    }
}

// ===========================================================================
// k3: BatchNorm(eval) + decoder GEMV + log_softmax.
// ===========================================================================
__global__ __launch_bounds__(128) void k3_out(
    const float* __restrict__ hws,
    const float* __restrict__ dW, const float* __restrict__ db,
    const float* __restrict__ bng, const float* __restrict__ bnb,
    float* __restrict__ out)
{
    __shared__ float hb[H_];
    __shared__ float red[O_];
    const int tid = threadIdx.x;
    const int b = blockIdx.x;
    const float s = 0.9999950000374997f;   // 1/sqrt(1 + 1e-5)
    for (int k = tid; k < H_; k += O_) {
        float v = hws[(size_t)b * H_ + k] * s * bng[k] + bnb[k];
        hb[k] = v;
        out[B_ * O_ + (size_t)b * H_ + k] = v;
    }
    __syncthreads();
    float acc = db[tid];
    #pragma unroll 4
    for (int k = 0; k < H_; ++k) acc += hb[k] * dW[(size_t)k * O_ + tid];
    red[tid] = acc;
    __syncthreads();
    for (int sh = 64; sh > 0; sh >>= 1) {
        if (tid < sh) red[tid] = fmaxf(red[tid], red[tid + sh]);
        __syncthreads();
    }
    float mx = red[0];
    __syncthreads();
    red[tid] = __expf(acc - mx);
    __syncthreads();
    for (int sh = 64; sh > 0; sh >>= 1) {
        if (tid < sh) red[tid] += red[tid + sh];
        __syncthreads();
    }
    float lse = __logf(red[0]) + mx;
    out[(size_t)b * O_ + tid] = acc - lse;
}

extern "C" void kernel_launch(void* const* d_in, const int* in_sizes, int n_in,
                              void* d_out, int out_size, void* d_ws, size_t ws_size,
                              hipStream_t stream)
{
    (void)in_sizes; (void)n_in; (void)out_size; (void)ws_size;
    const float* x   = (const float*)d_in[0];
    const float* dl  = (const float*)d_in[1];
    const float* m   = (const float*)d_in[2];
    const float* xf  = (const float*)d_in[3];
    const float* Wr  = (const float*)d_in[4];
    const float* Ur  = (const float*)d_in[5];
    const float* Vr  = (const float*)d_in[6];
    const float* br  = (const float*)d_in[7];
    const float* Wz  = (const float*)d_in[8];
    const float* Uz  = (const float*)d_in[9];
    const float* Vz  = (const float*)d_in[10];
    const float* bz  = (const float*)d_in[11];
    const float* Wc  = (const float*)d_in[12];
    const float* Uc  = (const float*)d_in[13];
    const float* Vc  = (const float*)d_in[14];
    const float* bc  = (const float*)d_in[15];
    const float* Wgx = (const float*)d_in[16];
    const float* Bgx = (const float*)d_in[17];
    const float* Wgh = (const float*)d_in[18];
    const float* Bgh = (const float*)d_in[19];
    const float* dW  = (const float*)d_in[20];
    const float* db  = (const float*)d_in[21];
    const float* bng = (const float*)d_in[22];
    const float* bnb = (const float*)d_in[23];

    char* p = (char*)d_ws;
    short* PW = (short*)p;              p += (size_t)3 * 256 * 64 * 8 * 2;   // 768 KB
    short* PG = (short*)p;              p += (size_t)128 * 64 * 8 * 2;       // 128 KB
    short* PUc = (short*)p;             p += (size_t)512 * 64 * 8 * 2;       // 512 KB
    unsigned char* PU8 = (unsigned char*)p; p += (size_t)1024 * 64 * 8;      // 512 KB
    bfu* buf0 = (bfu*)p;                p += 4 * SLOTS * 2;                  // 16 MB
    bfu* buf1 = (bfu*)p;                p += 4 * SLOTS * 2;                  // 16 MB
    float* hws = (float*)p;             p += (size_t)B_ * H_ * 4;            // 512 KB
    float* zx  = (float*)p;             p += (size_t)16 * 2 * 2 * 4096 * 4;  // 1 MB
    float* cx  = (float*)p;             p += (size_t)16 * 2 * 2 * 8192 * 4;  // 2 MB
    u32* flags = (u32*)p;                                                    // 4 KB

    hipMemsetAsync(hws, 0, (size_t)B_ * H_ * sizeof(float), stream);
    hipMemsetAsync(flags, 0, (size_t)32 * 32 * sizeof(u32), stream);
    k_pack<<<dim3(608), dim3(256), 0, stream>>>(Wz, Wr, Wc, Vz, Vr, Vc, Wgh,
                                                Uz, Ur, Uc, PW, PG, PUc, PU8);
    for (int c = 0; c <= NCH; ++c) {
        k_fused<<<dim3(160), dim3(1024), 0, stream>>>(c,
            x, dl, m, xf, bz, br, bc, Bgh, Wgx, Bgx,
            PW, PG, PUc, PU8, buf0, buf1, hws, zx, cx, flags);
    }
    k3_out<<<dim3(B_), dim3(O_), 0, stream>>>(hws, dW, db, bng, bnb, (float*)d_out);
}